// Round 10
// baseline (163.770 us; speedup 1.0000x reference)
//
#include <hip/hip_runtime.h>
#include <cmath>

#define BB  4
#define VV  4096
#define KK  40
#define FIN 64

typedef float v2f __attribute__((ext_vector_type(2)));

// ---------------------------------------------------------------------------
// Kernel A: 4 rows per wave (unchanged).
// ---------------------------------------------------------------------------
__global__ __launch_bounds__(256) void prep_kernel(
    const float* __restrict__ x, const float* __restrict__ Wf,
    const float* __restrict__ bf, const float* __restrict__ Ws,
    const float* __restrict__ bs,
    float* __restrict__ coords, float* __restrict__ sq,
    float* __restrict__ feats)
{
    int lane = threadIdx.x & 63;
    int wid  = threadIdx.x >> 6;
    int row0 = (blockIdx.x * 4 + wid) * 4;        // 4 rows per wave
    const float* xr = x + (size_t)row0 * FIN;

    float a0 = 0.f, a1 = 0.f, a2 = 0.f, a3 = 0.f;
    #pragma unroll 8
    for (int k = 0; k < FIN; ++k) {
        float wf = Wf[k * 64 + lane];              // one coalesced 256B row
        a0 = fmaf(xr[k],        wf, a0);           // x: wave-uniform loads
        a1 = fmaf(xr[64  + k],  wf, a1);
        a2 = fmaf(xr[128 + k],  wf, a2);
        a3 = fmaf(xr[192 + k],  wf, a3);
    }
    float bfl = bf[lane];
    feats[(size_t)(row0 + 0) * 64 + lane] = a0 + bfl;
    feats[(size_t)(row0 + 1) * 64 + lane] = a1 + bfl;
    feats[(size_t)(row0 + 2) * 64 + lane] = a2 + bfl;
    feats[(size_t)(row0 + 3) * 64 + lane] = a3 + bfl;

    // coords + sq for the same 4 rows
    int r  = lane >> 4;                            // 0..3 row
    int s  = (lane >> 2) & 3;                      // 0..3 coord dim
    int kc = lane & 3;                             // 0..3 k-chunk
    const float* xrr = x + (size_t)(row0 + r) * FIN + kc * 16;
    const float* wsr = Ws + kc * 16 * 4 + s;
    float c = 0.f;
    #pragma unroll
    for (int k = 0; k < 16; ++k)
        c = fmaf(xrr[k], wsr[k * 4], c);
    c += __shfl_xor(c, 1, 64);                     // reduce over kc
    c += __shfl_xor(c, 2, 64);
    float val = c + bs[s];
    if ((lane & 3) == 0) coords[(size_t)(row0 + r) * 4 + s] = val;
    float p = val * val;
    p += __shfl_xor(p, 4, 64);                     // reduce over s
    p += __shfl_xor(p, 8, 64);
    if ((lane & 15) == 0) sq[row0 + r] = p;
}

// ---------------------------------------------------------------------------
// Spill-proof helpers: ALL state passed as explicit register values.
// (Round-9 lesson: runtime-indexed local arrays -> scratch -> 238 MB of
//  HBM spill traffic. Never index selection state dynamically.)
// ---------------------------------------------------------------------------
__device__ __forceinline__ int cnt_lt4(unsigned m0, unsigned m1,
                                       unsigned m2, unsigned m3,
                                       unsigned cand)
{
    return (int)__popcll(__ballot(m0 < cand))
         + (int)__popcll(__ballot(m1 < cand))
         + (int)__popcll(__ballot(m2 < cand))
         + (int)__popcll(__ballot(m3 < cand));
}

__device__ __forceinline__ unsigned fallback12(unsigned m0, unsigned m1,
                                               unsigned m2, unsigned m3,
                                               unsigned M)
{
    #pragma unroll
    for (int bit = 11; bit >= 0; --bit) {
        unsigned cand = M | (1u << bit);
        if (cnt_lt4(m0, m1, m2, m3, cand) <= 39) M = cand;
    }
    return M;
}

// drop rank-0 (global min, robust) + compact 39 {off,w} entries to LDS
__device__ __forceinline__ void compact4(unsigned m0, unsigned m1,
                                         unsigned m2, unsigned m3,
                                         unsigned Msel, uint2* dst)
{
    unsigned mn = m0;
    #pragma unroll
    for (int off = 32; off >= 1; off >>= 1) {
        unsigned o = __shfl_xor(mn, off, 64);
        mn = o < mn ? o : mn;
    }
    int base = 0;
    unsigned kk = m0;
    #pragma unroll
    for (int i = 0; i < 4; ++i) {
        bool pred = (kk <= Msel) && (kk != mn);
        unsigned long long mask = __ballot(pred);
        unsigned pos = (unsigned)base +
            __builtin_amdgcn_mbcnt_hi((unsigned)(mask >> 32),
                __builtin_amdgcn_mbcnt_lo((unsigned)mask, 0u));
        if (pred) {
            float d2a = __uint_as_float(kk & 0xFFFFF000u);
            float w   = __expf(-10.f * d2a);
            dst[pos] = make_uint2((kk & 4095u) << 8, __float_as_uint(w));
        }
        base += (int)__popcll(mask);
        kk = (i == 0) ? m1 : (i == 1) ? m2 : m3;   // static rotation
    }
}

// ---------------------------------------------------------------------------
// Kernel B: one wave per TWO consecutive queries.
//   19-step value-bit radix (+ rare exact 12-step index fallback, wave-
//   uniform branch) for the rank-39 key; gather(q0) fused with radix(q1)
//   so q1's serial SALU chain hides under q0's gather VMEM.
//   No __syncthreads: all LDS use is same-wave.
// ---------------------------------------------------------------------------
__global__ __launch_bounds__(256, 8) void gravnet_kernel(
    const float* __restrict__ x, const float* __restrict__ coords,
    const float* __restrict__ sq, const float* __restrict__ feats,
    const float* __restrict__ Wo, const float* __restrict__ bo,
    float* __restrict__ out)
{
    int lane = threadIdx.x & 63;
    int wid  = threadIdx.x >> 6;
    int q0   = (blockIdx.x * 4 + wid) * 2;        // first of 2 queries
    int b    = q0 >> 12;
    int v0   = q0 & (VV - 1);

    __shared__ uint2               s_nb[4][2][KK];   // {u*256, bits(w)}
    __shared__ __align__(16) float s_upd[4][2][192];

    const float4* cb  = (const float4*)(coords + (size_t)b * VV * 4);
    const float*  sqb = sq + (size_t)b * VV;

    // pair-packed query constants: n* = -2*cq, hs = sqv  (lane-uniform)
    float4 cqa = cb[v0], cqb = cb[v0 + 1];
    v2f nx = (v2f){-2.f * cqa.x, -2.f * cqb.x};
    v2f ny = (v2f){-2.f * cqa.y, -2.f * cqb.y};
    v2f nz = (v2f){-2.f * cqa.z, -2.f * cqb.z};
    v2f nw = (v2f){-2.f * cqa.w, -2.f * cqb.w};
    v2f hs = (v2f){sqb[v0], sqb[v0 + 1]};

    // --- distance + key + per-lane top-4 for 2 queries (explicit scalars)
    unsigned a0k = 0xFFFFFFFFu, a1k = 0xFFFFFFFFu,
             a2k = 0xFFFFFFFFu, a3k = 0xFFFFFFFFu;   // q0
    unsigned b0k = 0xFFFFFFFFu, b1k = 0xFFFFFFFFu,
             b2k = 0xFFFFFFFFu, b3k = 0xFFFFFFFFu;   // q1

    #pragma unroll 4
    for (int i = 0; i < 64; ++i) {
        int u = i * 64 + lane;
        float4 cu = cb[u];
        float squ = sqb[u];                        // precomputed |c_u|^2
        v2f acc = hs + (v2f){squ, squ};            // pk_add
        acc = __builtin_elementwise_fma(nx, (v2f){cu.x, cu.x}, acc);
        acc = __builtin_elementwise_fma(ny, (v2f){cu.y, cu.y}, acc);
        acc = __builtin_elementwise_fma(nz, (v2f){cu.z, cu.z}, acc);
        acc = __builtin_elementwise_fma(nw, (v2f){cu.w, cu.w}, acc);

        float d2a = fmaxf(acc.x, 0.f);             // keys non-negative
        unsigned ka = (__float_as_uint(d2a) & 0xFFFFF000u) | (unsigned)u;
        unsigned t0 = max(a0k, ka);
        unsigned t1 = max(a1k, ka);
        unsigned t2 = max(a2k, ka);
        a0k = min(a0k, ka);
        a1k = min(a1k, t0);
        a2k = min(a2k, t1);
        a3k = min(a3k, t2);

        float d2b = fmaxf(acc.y, 0.f);
        unsigned kb = (__float_as_uint(d2b) & 0xFFFFF000u) | (unsigned)u;
        unsigned s0 = max(b0k, kb);
        unsigned s1 = max(b1k, kb);
        unsigned s2 = max(b2k, kb);
        b0k = min(b0k, kb);
        b1k = min(b1k, s0);
        b2k = min(b2k, s1);
        b3k = min(b3k, s2);
    }

    // --- q0: 19-step value radix + rare exact fallback, compact
    unsigned M0 = 0u;
    #pragma unroll
    for (int bit = 30; bit >= 12; --bit) {
        unsigned cand = M0 | (1u << bit);
        if (cnt_lt4(a0k, a1k, a2k, a3k, cand) <= 39) M0 = cand;
    }
    unsigned Msel0 = M0 | 0xFFFu;
    if (cnt_lt4(a0k, a1k, a2k, a3k, M0 + 4096u) != 40) {
        M0 = fallback12(a0k, a1k, a2k, a3k, M0);
        Msel0 = M0;
    }
    compact4(a0k, a1k, a2k, a3k, Msel0, &s_nb[wid][0][0]);
    // same-wave LDS write->read: no barrier needed

    // --- fused: gather(q0) || radix-19(q1)
    const float* fb  = feats + (size_t)b * VV * 64;    // uniform base
    unsigned     ln4 = (unsigned)lane * 4u;
    float vmax0 = -INFINITY, vsum0 = 0.f;
    unsigned M1 = 0u;
    #pragma unroll
    for (int j = 0; j < KK - 1; ++j) {
        uint2 nb = s_nb[wid][0][j];                // ds_read_b64
        float f  = *(const float*)((const char*)fb + (nb.x + ln4));
        float val = __uint_as_float(nb.y) * f;
        vmax0 = fmaxf(vmax0, val);
        vsum0 += val;
        if (j < 19) {                              // q1 radix bit 30-j
            unsigned cand = M1 | (1u << (30 - j));
            if (cnt_lt4(b0k, b1k, b2k, b3k, cand) <= 39) M1 = cand;
        }
    }
    unsigned Msel1 = M1 | 0xFFFu;
    if (cnt_lt4(b0k, b1k, b2k, b3k, M1 + 4096u) != 40) {
        M1 = fallback12(b0k, b1k, b2k, b3k, M1);
        Msel1 = M1;
    }
    compact4(b0k, b1k, b2k, b3k, Msel1, &s_nb[wid][1][0]);

    // --- gather q1
    float vmax1 = -INFINITY, vsum1 = 0.f;
    #pragma unroll
    for (int j = 0; j < KK - 1; ++j) {
        uint2 nb = s_nb[wid][1][j];
        float f  = *(const float*)((const char*)fb + (nb.x + ln4));
        float val = __uint_as_float(nb.y) * f;
        vmax1 = fmaxf(vmax1, val);
        vsum1 += val;
    }

    // --- updated vectors to LDS
    s_upd[wid][0][lane]       = x[(size_t)q0 * 64 + lane];
    s_upd[wid][0][64  + lane] = vmax0;
    s_upd[wid][0][128 + lane] = vsum0 * (1.0f / 39.0f);
    s_upd[wid][1][lane]       = x[(size_t)(q0 + 1) * 64 + lane];
    s_upd[wid][1][64  + lane] = vmax1;
    s_upd[wid][1][128 + lane] = vsum1 * (1.0f / 39.0f);

    // --- GEMV (192 x 64) x 2: Wo row loaded once, 2 fma each
    float bol = bo[lane];
    float acc0 = bol, acc1 = bol;
    #pragma unroll 4
    for (int j4 = 0; j4 < 48; ++j4) {
        float wo0 = Wo[(j4 * 4 + 0) * 64 + lane];
        float wo1 = Wo[(j4 * 4 + 1) * 64 + lane];
        float wo2 = Wo[(j4 * 4 + 2) * 64 + lane];
        float wo3 = Wo[(j4 * 4 + 3) * 64 + lane];
        float4 u0 = *(const float4*)&s_upd[wid][0][j4 * 4]; // LDS bcast
        float4 u1 = *(const float4*)&s_upd[wid][1][j4 * 4];
        acc0 = fmaf(u0.x, wo0, acc0);  acc1 = fmaf(u1.x, wo0, acc1);
        acc0 = fmaf(u0.y, wo1, acc0);  acc1 = fmaf(u1.y, wo1, acc1);
        acc0 = fmaf(u0.z, wo2, acc0);  acc1 = fmaf(u1.z, wo2, acc1);
        acc0 = fmaf(u0.w, wo3, acc0);  acc1 = fmaf(u1.w, wo3, acc1);
    }
    float e0 = __expf(2.f * acc0);                 // tanh = 1 - 2/(e^2x+1)
    float e1 = __expf(2.f * acc1);
    out[(size_t)q0 * 64 + lane]       = 1.f - __fdividef(2.f, e0 + 1.f);
    out[(size_t)(q0 + 1) * 64 + lane] = 1.f - __fdividef(2.f, e1 + 1.f);
}

// ---------------------------------------------------------------------------
extern "C" void kernel_launch(void* const* d_in, const int* in_sizes, int n_in,
                              void* d_out, int out_size, void* d_ws, size_t ws_size,
                              hipStream_t stream)
{
    (void)in_sizes; (void)n_in; (void)out_size; (void)ws_size;
    const float* x  = (const float*)d_in[0];
    const float* Wf = (const float*)d_in[1];
    const float* bf = (const float*)d_in[2];
    const float* Ws = (const float*)d_in[3];
    const float* bs = (const float*)d_in[4];
    const float* Wo = (const float*)d_in[5];
    const float* bo = (const float*)d_in[6];
    float* out = (float*)d_out;

    float* coords = (float*)d_ws;                     // B*V*4  floats (256 KB)
    float* sq     = coords + (size_t)BB * VV * 4;     // B*V    floats (64 KB)
    float* feats  = sq + (size_t)BB * VV;             // B*V*64 floats (4 MB)

    prep_kernel<<<BB * VV / 16, 256, 0, stream>>>(x, Wf, bf, Ws, bs,
                                                  coords, sq, feats);
    gravnet_kernel<<<BB * VV / 8, 256, 0, stream>>>(x, coords, sq, feats,
                                                    Wo, bo, out);
}

// Round 11
// 126.965 us; speedup vs baseline: 1.2899x; 1.2899x over previous
//
#include <hip/hip_runtime.h>
#include <cmath>

#define BB  4
#define VV  4096
#define KK  40
#define FIN 64

typedef float v2f __attribute__((ext_vector_type(2)));

// ---------------------------------------------------------------------------
// Kernel A: 4 rows per wave (unchanged).
// ---------------------------------------------------------------------------
__global__ __launch_bounds__(256) void prep_kernel(
    const float* __restrict__ x, const float* __restrict__ Wf,
    const float* __restrict__ bf, const float* __restrict__ Ws,
    const float* __restrict__ bs,
    float* __restrict__ coords, float* __restrict__ sq,
    float* __restrict__ feats)
{
    int lane = threadIdx.x & 63;
    int wid  = threadIdx.x >> 6;
    int row0 = (blockIdx.x * 4 + wid) * 4;        // 4 rows per wave
    const float* xr = x + (size_t)row0 * FIN;

    float a0 = 0.f, a1 = 0.f, a2 = 0.f, a3 = 0.f;
    #pragma unroll 8
    for (int k = 0; k < FIN; ++k) {
        float wf = Wf[k * 64 + lane];              // one coalesced 256B row
        a0 = fmaf(xr[k],        wf, a0);           // x: wave-uniform loads
        a1 = fmaf(xr[64  + k],  wf, a1);
        a2 = fmaf(xr[128 + k],  wf, a2);
        a3 = fmaf(xr[192 + k],  wf, a3);
    }
    float bfl = bf[lane];
    feats[(size_t)(row0 + 0) * 64 + lane] = a0 + bfl;
    feats[(size_t)(row0 + 1) * 64 + lane] = a1 + bfl;
    feats[(size_t)(row0 + 2) * 64 + lane] = a2 + bfl;
    feats[(size_t)(row0 + 3) * 64 + lane] = a3 + bfl;

    // coords + sq for the same 4 rows
    int r  = lane >> 4;                            // 0..3 row
    int s  = (lane >> 2) & 3;                      // 0..3 coord dim
    int kc = lane & 3;                             // 0..3 k-chunk
    const float* xrr = x + (size_t)(row0 + r) * FIN + kc * 16;
    const float* wsr = Ws + kc * 16 * 4 + s;
    float c = 0.f;
    #pragma unroll
    for (int k = 0; k < 16; ++k)
        c = fmaf(xrr[k], wsr[k * 4], c);
    c += __shfl_xor(c, 1, 64);                     // reduce over kc
    c += __shfl_xor(c, 2, 64);
    float val = c + bs[s];
    if ((lane & 3) == 0) coords[(size_t)(row0 + r) * 4 + s] = val;
    float p = val * val;
    p += __shfl_xor(p, 4, 64);                     // reduce over s
    p += __shfl_xor(p, 8, 64);
    if ((lane & 15) == 0) sq[row0 + r] = p;
}

// ---------------------------------------------------------------------------
// Spill-proof helpers: explicit scalar args only (round-9/10 lesson:
// runtime-indexed locals and fused full-unroll loops -> scratch spill).
// ---------------------------------------------------------------------------
__device__ __forceinline__ unsigned umed3(unsigned a, unsigned b, unsigned c)
{
    unsigned d;
    asm("v_med3_u32 %0, %1, %2, %3" : "=v"(d) : "v"(a), "v"(b), "v"(c));
    return d;
}

__device__ __forceinline__ int cnt_lt4(unsigned m0, unsigned m1,
                                       unsigned m2, unsigned m3,
                                       unsigned cand)
{
    return (int)__popcll(__ballot(m0 < cand))
         + (int)__popcll(__ballot(m1 < cand))
         + (int)__popcll(__ballot(m2 < cand))
         + (int)__popcll(__ballot(m3 < cand));
}

// rank-39 threshold: 19 value-bit radix steps; exact 12-step index-bit
// fallback only when the 20-bit boundary prefix is shared (rare, wave-
// uniform branch). Returns Msel: selected set = {key <= Msel}, |set| = 40.
__device__ __forceinline__ unsigned select_thresh(unsigned m0, unsigned m1,
                                                  unsigned m2, unsigned m3)
{
    unsigned M = 0u;
    #pragma unroll
    for (int bit = 30; bit >= 12; --bit) {
        unsigned cand = M | (1u << bit);
        if (cnt_lt4(m0, m1, m2, m3, cand) <= 39) M = cand;
    }
    unsigned Msel = M | 0xFFFu;
    if (cnt_lt4(m0, m1, m2, m3, M + 4096u) != 40) {
        #pragma unroll
        for (int bit = 11; bit >= 0; --bit) {
            unsigned cand = M | (1u << bit);
            if (cnt_lt4(m0, m1, m2, m3, cand) <= 39) M = cand;
        }
        Msel = M;
    }
    return Msel;
}

// drop rank-0 (global min, robust -- round-4 lesson) + compact the other 39
// as predecoded {byte_offset = u*256, weight = exp(-10*d2)} into LDS
__device__ __forceinline__ void compact4(unsigned m0, unsigned m1,
                                         unsigned m2, unsigned m3,
                                         unsigned Msel, uint2* dst)
{
    unsigned mn = m0;
    #pragma unroll
    for (int off = 32; off >= 1; off >>= 1) {
        unsigned o = __shfl_xor(mn, off, 64);
        mn = o < mn ? o : mn;
    }
    int base = 0;
    unsigned kk = m0;
    #pragma unroll
    for (int i = 0; i < 4; ++i) {
        bool pred = (kk <= Msel) && (kk != mn);
        unsigned long long mask = __ballot(pred);
        unsigned pos = (unsigned)base +
            __builtin_amdgcn_mbcnt_hi((unsigned)(mask >> 32),
                __builtin_amdgcn_mbcnt_lo((unsigned)mask, 0u));
        if (pred) {
            float d2a = __uint_as_float(kk & 0xFFFFF000u);
            float w   = __expf(-10.f * d2a);
            dst[pos] = make_uint2((kk & 4095u) << 8, __float_as_uint(w));
        }
        base += (int)__popcll(mask);
        kk = (i == 0) ? m1 : (i == 1) ? m2 : m3;   // static rotation
    }
}

// ---------------------------------------------------------------------------
// Kernel B: one wave per FOUR consecutive queries (round-7 structure — the
// best measured, spill-free config). Candidate stream shared by 4 queries;
// pair-packed pk_fma distance; 4-op med3 insertion (depth 1); 19-step radix;
// predecoded gather; Wo-shared GEMV. Phases strictly sequential (fusion
// abandoned: twice caused live-range spill). No __syncthreads (same-wave LDS).
// ---------------------------------------------------------------------------
__global__ __launch_bounds__(256) void gravnet_kernel(
    const float* __restrict__ x, const float* __restrict__ coords,
    const float* __restrict__ sq, const float* __restrict__ feats,
    const float* __restrict__ Wo, const float* __restrict__ bo,
    float* __restrict__ out)
{
    int lane = threadIdx.x & 63;
    int wid  = threadIdx.x >> 6;
    int q0   = (blockIdx.x * 4 + wid) * 4;        // first of 4 queries
    int b    = q0 >> 12;
    int v0   = q0 & (VV - 1);

    __shared__ uint2               s_nb[4][4][KK];   // {u*256, bits(w)}
    __shared__ __align__(16) float s_upd[4][4][192];

    const float4* cb  = (const float4*)(coords + (size_t)b * VV * 4);
    const float*  sqb = sq + (size_t)b * VV;

    // pair-packed query constants: n* = -2*cq, hs = sqv  (lane-uniform)
    float4 cq0 = cb[v0],     cq1 = cb[v0 + 1];
    float4 cq2 = cb[v0 + 2], cq3 = cb[v0 + 3];
    v2f nxA = (v2f){-2.f * cq0.x, -2.f * cq1.x};
    v2f nyA = (v2f){-2.f * cq0.y, -2.f * cq1.y};
    v2f nzA = (v2f){-2.f * cq0.z, -2.f * cq1.z};
    v2f nwA = (v2f){-2.f * cq0.w, -2.f * cq1.w};
    v2f hsA = (v2f){sqb[v0], sqb[v0 + 1]};
    v2f nxB = (v2f){-2.f * cq2.x, -2.f * cq3.x};
    v2f nyB = (v2f){-2.f * cq2.y, -2.f * cq3.y};
    v2f nzB = (v2f){-2.f * cq2.z, -2.f * cq3.z};
    v2f nwB = (v2f){-2.f * cq2.w, -2.f * cq3.w};
    v2f hsB = (v2f){sqb[v0 + 2], sqb[v0 + 3]};

    // per-lane top-4 keys per query, individually named (spill-proof)
    unsigned k00 = ~0u, k01 = ~0u, k02 = ~0u, k03 = ~0u;   // q0
    unsigned k10 = ~0u, k11 = ~0u, k12 = ~0u, k13 = ~0u;   // q1
    unsigned k20 = ~0u, k21 = ~0u, k22 = ~0u, k23 = ~0u;   // q2
    unsigned k30 = ~0u, k31 = ~0u, k32 = ~0u, k33 = ~0u;   // q3

    #pragma unroll 4
    for (int i = 0; i < 64; ++i) {
        int u = i * 64 + lane;
        float4 cu = cb[u];
        float squ = sqb[u];                        // precomputed |c_u|^2
        v2f accA = hsA + (v2f){squ, squ};          // pk_add
        accA = __builtin_elementwise_fma(nxA, (v2f){cu.x, cu.x}, accA);
        accA = __builtin_elementwise_fma(nyA, (v2f){cu.y, cu.y}, accA);
        accA = __builtin_elementwise_fma(nzA, (v2f){cu.z, cu.z}, accA);
        accA = __builtin_elementwise_fma(nwA, (v2f){cu.w, cu.w}, accA);
        v2f accB = hsB + (v2f){squ, squ};
        accB = __builtin_elementwise_fma(nxB, (v2f){cu.x, cu.x}, accB);
        accB = __builtin_elementwise_fma(nyB, (v2f){cu.y, cu.y}, accB);
        accB = __builtin_elementwise_fma(nzB, (v2f){cu.z, cu.z}, accB);
        accB = __builtin_elementwise_fma(nwB, (v2f){cu.w, cu.w}, accB);

        // q0: 4-op depth-1 insert (min + 3x v_med3_u32)
        {
            float d2 = fmaxf(accA.x, 0.f);
            unsigned k = (__float_as_uint(d2) & 0xFFFFF000u) | (unsigned)u;
            unsigned n1 = umed3(k00, k01, k);
            unsigned n2 = umed3(k01, k02, k);
            unsigned n3 = umed3(k02, k03, k);
            k00 = min(k00, k); k01 = n1; k02 = n2; k03 = n3;
        }
        { // q1
            float d2 = fmaxf(accA.y, 0.f);
            unsigned k = (__float_as_uint(d2) & 0xFFFFF000u) | (unsigned)u;
            unsigned n1 = umed3(k10, k11, k);
            unsigned n2 = umed3(k11, k12, k);
            unsigned n3 = umed3(k12, k13, k);
            k10 = min(k10, k); k11 = n1; k12 = n2; k13 = n3;
        }
        { // q2
            float d2 = fmaxf(accB.x, 0.f);
            unsigned k = (__float_as_uint(d2) & 0xFFFFF000u) | (unsigned)u;
            unsigned n1 = umed3(k20, k21, k);
            unsigned n2 = umed3(k21, k22, k);
            unsigned n3 = umed3(k22, k23, k);
            k20 = min(k20, k); k21 = n1; k22 = n2; k23 = n3;
        }
        { // q3
            float d2 = fmaxf(accB.y, 0.f);
            unsigned k = (__float_as_uint(d2) & 0xFFFFF000u) | (unsigned)u;
            unsigned n1 = umed3(k30, k31, k);
            unsigned n2 = umed3(k31, k32, k);
            unsigned n3 = umed3(k32, k33, k);
            k30 = min(k30, k); k31 = n1; k32 = n2; k33 = n3;
        }
    }

    // --- select + compact, per query (sequential; ~20 ballot steps each)
    compact4(k00, k01, k02, k03, select_thresh(k00, k01, k02, k03),
             &s_nb[wid][0][0]);
    compact4(k10, k11, k12, k13, select_thresh(k10, k11, k12, k13),
             &s_nb[wid][1][0]);
    compact4(k20, k21, k22, k23, select_thresh(k20, k21, k22, k23),
             &s_nb[wid][2][0]);
    compact4(k30, k31, k32, k33, select_thresh(k30, k31, k32, k33),
             &s_nb[wid][3][0]);
    // same-wave LDS write->read: no barrier needed

    // --- gather 39 neighbours x 4 queries, weighted max + sum
    const float* fb  = feats + (size_t)b * VV * 64;
    const char*  fbl = (const char*)(fb + lane);   // lane offset baked in
    float vmax0 = -INFINITY, vsum0 = 0.f, vmax1 = -INFINITY, vsum1 = 0.f;
    float vmax2 = -INFINITY, vsum2 = 0.f, vmax3 = -INFINITY, vsum3 = 0.f;
    #pragma unroll 3
    for (int j = 0; j < KK - 1; ++j) {
        uint2 n0 = s_nb[wid][0][j];                // ds_read_b64 x4
        uint2 n1 = s_nb[wid][1][j];
        uint2 n2 = s_nb[wid][2][j];
        uint2 n3 = s_nb[wid][3][j];
        float f0 = *(const float*)(fbl + n0.x);
        float f1 = *(const float*)(fbl + n1.x);
        float f2 = *(const float*)(fbl + n2.x);
        float f3 = *(const float*)(fbl + n3.x);
        float v0g = __uint_as_float(n0.y) * f0;
        float v1g = __uint_as_float(n1.y) * f1;
        float v2g = __uint_as_float(n2.y) * f2;
        float v3g = __uint_as_float(n3.y) * f3;
        vmax0 = fmaxf(vmax0, v0g); vsum0 += v0g;
        vmax1 = fmaxf(vmax1, v1g); vsum1 += v1g;
        vmax2 = fmaxf(vmax2, v2g); vsum2 += v2g;
        vmax3 = fmaxf(vmax3, v3g); vsum3 += v3g;
    }

    // --- updated vectors to LDS
    s_upd[wid][0][lane]       = x[(size_t)(q0 + 0) * 64 + lane];
    s_upd[wid][0][64  + lane] = vmax0;
    s_upd[wid][0][128 + lane] = vsum0 * (1.0f / 39.0f);
    s_upd[wid][1][lane]       = x[(size_t)(q0 + 1) * 64 + lane];
    s_upd[wid][1][64  + lane] = vmax1;
    s_upd[wid][1][128 + lane] = vsum1 * (1.0f / 39.0f);
    s_upd[wid][2][lane]       = x[(size_t)(q0 + 2) * 64 + lane];
    s_upd[wid][2][64  + lane] = vmax2;
    s_upd[wid][2][128 + lane] = vsum2 * (1.0f / 39.0f);
    s_upd[wid][3][lane]       = x[(size_t)(q0 + 3) * 64 + lane];
    s_upd[wid][3][64  + lane] = vmax3;
    s_upd[wid][3][128 + lane] = vsum3 * (1.0f / 39.0f);

    // --- GEMV (192 x 64) x 4: Wo row loaded once, 4 fma each
    float bol = bo[lane];
    float acc0 = bol, acc1 = bol, acc2 = bol, acc3 = bol;
    #pragma unroll 4
    for (int j4 = 0; j4 < 48; ++j4) {
        float wo0 = Wo[(j4 * 4 + 0) * 64 + lane];
        float wo1 = Wo[(j4 * 4 + 1) * 64 + lane];
        float wo2 = Wo[(j4 * 4 + 2) * 64 + lane];
        float wo3 = Wo[(j4 * 4 + 3) * 64 + lane];
        float4 u0 = *(const float4*)&s_upd[wid][0][j4 * 4]; // LDS bcast
        float4 u1 = *(const float4*)&s_upd[wid][1][j4 * 4];
        float4 u2 = *(const float4*)&s_upd[wid][2][j4 * 4];
        float4 u3 = *(const float4*)&s_upd[wid][3][j4 * 4];
        acc0 = fmaf(u0.x, wo0, acc0);  acc1 = fmaf(u1.x, wo0, acc1);
        acc2 = fmaf(u2.x, wo0, acc2);  acc3 = fmaf(u3.x, wo0, acc3);
        acc0 = fmaf(u0.y, wo1, acc0);  acc1 = fmaf(u1.y, wo1, acc1);
        acc2 = fmaf(u2.y, wo1, acc2);  acc3 = fmaf(u3.y, wo1, acc3);
        acc0 = fmaf(u0.z, wo2, acc0);  acc1 = fmaf(u1.z, wo2, acc1);
        acc2 = fmaf(u2.z, wo2, acc2);  acc3 = fmaf(u3.z, wo2, acc3);
        acc0 = fmaf(u0.w, wo3, acc0);  acc1 = fmaf(u1.w, wo3, acc1);
        acc2 = fmaf(u2.w, wo3, acc2);  acc3 = fmaf(u3.w, wo3, acc3);
    }
    float e0 = __expf(2.f * acc0);                 // tanh = 1 - 2/(e^2x+1)
    float e1 = __expf(2.f * acc1);
    float e2 = __expf(2.f * acc2);
    float e3 = __expf(2.f * acc3);
    out[(size_t)(q0 + 0) * 64 + lane] = 1.f - __fdividef(2.f, e0 + 1.f);
    out[(size_t)(q0 + 1) * 64 + lane] = 1.f - __fdividef(2.f, e1 + 1.f);
    out[(size_t)(q0 + 2) * 64 + lane] = 1.f - __fdividef(2.f, e2 + 1.f);
    out[(size_t)(q0 + 3) * 64 + lane] = 1.f - __fdividef(2.f, e3 + 1.f);
}

// ---------------------------------------------------------------------------
extern "C" void kernel_launch(void* const* d_in, const int* in_sizes, int n_in,
                              void* d_out, int out_size, void* d_ws, size_t ws_size,
                              hipStream_t stream)
{
    (void)in_sizes; (void)n_in; (void)out_size; (void)ws_size;
    const float* x  = (const float*)d_in[0];
    const float* Wf = (const float*)d_in[1];
    const float* bf = (const float*)d_in[2];
    const float* Ws = (const float*)d_in[3];
    const float* bs = (const float*)d_in[4];
    const float* Wo = (const float*)d_in[5];
    const float* bo = (const float*)d_in[6];
    float* out = (float*)d_out;

    float* coords = (float*)d_ws;                     // B*V*4  floats (256 KB)
    float* sq     = coords + (size_t)BB * VV * 4;     // B*V    floats (64 KB)
    float* feats  = sq + (size_t)BB * VV;             // B*V*64 floats (4 MB)

    prep_kernel<<<BB * VV / 16, 256, 0, stream>>>(x, Wf, bf, Ws, bs,
                                                  coords, sq, feats);
    gravnet_kernel<<<BB * VV / 16, 256, 0, stream>>>(x, coords, sq, feats,
                                                     Wo, bo, out);
}

// Round 12
// 124.046 us; speedup vs baseline: 1.3202x; 1.0235x over previous
//
#include <hip/hip_runtime.h>
#include <cmath>

#define BB  4
#define VV  4096
#define KK  40
#define FIN 64

typedef float v2f __attribute__((ext_vector_type(2)));

// ---------------------------------------------------------------------------
// Kernel A: 4 rows per wave (unchanged).
// ---------------------------------------------------------------------------
__global__ __launch_bounds__(256) void prep_kernel(
    const float* __restrict__ x, const float* __restrict__ Wf,
    const float* __restrict__ bf, const float* __restrict__ Ws,
    const float* __restrict__ bs,
    float* __restrict__ coords, float* __restrict__ sq,
    float* __restrict__ feats)
{
    int lane = threadIdx.x & 63;
    int wid  = threadIdx.x >> 6;
    int row0 = (blockIdx.x * 4 + wid) * 4;        // 4 rows per wave
    const float* xr = x + (size_t)row0 * FIN;

    float a0 = 0.f, a1 = 0.f, a2 = 0.f, a3 = 0.f;
    #pragma unroll 8
    for (int k = 0; k < FIN; ++k) {
        float wf = Wf[k * 64 + lane];              // one coalesced 256B row
        a0 = fmaf(xr[k],        wf, a0);           // x: wave-uniform loads
        a1 = fmaf(xr[64  + k],  wf, a1);
        a2 = fmaf(xr[128 + k],  wf, a2);
        a3 = fmaf(xr[192 + k],  wf, a3);
    }
    float bfl = bf[lane];
    feats[(size_t)(row0 + 0) * 64 + lane] = a0 + bfl;
    feats[(size_t)(row0 + 1) * 64 + lane] = a1 + bfl;
    feats[(size_t)(row0 + 2) * 64 + lane] = a2 + bfl;
    feats[(size_t)(row0 + 3) * 64 + lane] = a3 + bfl;

    // coords + sq for the same 4 rows
    int r  = lane >> 4;                            // 0..3 row
    int s  = (lane >> 2) & 3;                      // 0..3 coord dim
    int kc = lane & 3;                             // 0..3 k-chunk
    const float* xrr = x + (size_t)(row0 + r) * FIN + kc * 16;
    const float* wsr = Ws + kc * 16 * 4 + s;
    float c = 0.f;
    #pragma unroll
    for (int k = 0; k < 16; ++k)
        c = fmaf(xrr[k], wsr[k * 4], c);
    c += __shfl_xor(c, 1, 64);                     // reduce over kc
    c += __shfl_xor(c, 2, 64);
    float val = c + bs[s];
    if ((lane & 3) == 0) coords[(size_t)(row0 + r) * 4 + s] = val;
    float p = val * val;
    p += __shfl_xor(p, 4, 64);                     // reduce over s
    p += __shfl_xor(p, 8, 64);
    if ((lane & 15) == 0) sq[row0 + r] = p;
}

// ---------------------------------------------------------------------------
// Spill-proof helpers (rounds 9/10 lesson: no runtime-indexed locals).
// ---------------------------------------------------------------------------
__device__ __forceinline__ unsigned umed3(unsigned a, unsigned b, unsigned c)
{
    unsigned d;
    asm("v_med3_u32 %0, %1, %2, %3" : "=v"(d) : "v"(a), "v"(b), "v"(c));
    return d;
}

__device__ __forceinline__ int cnt_lt4(unsigned m0, unsigned m1,
                                       unsigned m2, unsigned m3,
                                       unsigned cand)
{
    return (int)__popcll(__ballot(m0 < cand))
         + (int)__popcll(__ballot(m1 < cand))
         + (int)__popcll(__ballot(m2 < cand))
         + (int)__popcll(__ballot(m3 < cand));
}

// rank-39 threshold: 19 value-bit radix steps; exact 12-step index-bit
// fallback only on a 20-bit boundary tie (rare, wave-uniform branch).
__device__ __forceinline__ unsigned select_thresh(unsigned m0, unsigned m1,
                                                  unsigned m2, unsigned m3)
{
    unsigned M = 0u;
    #pragma unroll
    for (int bit = 30; bit >= 12; --bit) {
        unsigned cand = M | (1u << bit);
        if (cnt_lt4(m0, m1, m2, m3, cand) <= 39) M = cand;
    }
    unsigned Msel = M | 0xFFFu;
    if (cnt_lt4(m0, m1, m2, m3, M + 4096u) != 40) {
        #pragma unroll
        for (int bit = 11; bit >= 0; --bit) {
            unsigned cand = M | (1u << bit);
            if (cnt_lt4(m0, m1, m2, m3, cand) <= 39) M = cand;
        }
        Msel = M;
    }
    return Msel;
}

// drop rank-0 (global min; m0 must hold the lane min) + compact the other 39
// as predecoded {byte_offset = u*256, weight = exp(-10*d2)} into LDS
__device__ __forceinline__ void compact4(unsigned m0, unsigned m1,
                                         unsigned m2, unsigned m3,
                                         unsigned Msel, uint2* dst)
{
    unsigned mn = m0;
    #pragma unroll
    for (int off = 32; off >= 1; off >>= 1) {
        unsigned o = __shfl_xor(mn, off, 64);
        mn = o < mn ? o : mn;
    }
    int base = 0;
    unsigned kk = m0;
    #pragma unroll
    for (int i = 0; i < 4; ++i) {
        bool pred = (kk <= Msel) && (kk != mn);
        unsigned long long mask = __ballot(pred);
        unsigned pos = (unsigned)base +
            __builtin_amdgcn_mbcnt_hi((unsigned)(mask >> 32),
                __builtin_amdgcn_mbcnt_lo((unsigned)mask, 0u));
        if (pred) {
            float d2a = __uint_as_float(kk & 0xFFFFF000u);
            float w   = __expf(-10.f * d2a);
            dst[pos] = make_uint2((kk & 4095u) << 8, __float_as_uint(w));
        }
        base += (int)__popcll(mask);
        kk = (i == 0) ? m1 : (i == 1) ? m2 : m3;   // static rotation
    }
}

// ---------------------------------------------------------------------------
// Kernel B (split-candidate waves): block = 4 waves = 8 queries.
//   Wave pair {2q, 2q+1} shares query-quad q; each wave runs the
//   distance + per-lane-top-4 loop over HALF the candidates (32 iters),
//   publishes its sorted quads to LDS (ds_write_b128), barrier, then merges
//   with the partner's via the bitonic-partner trick:
//   lowest-4 of sorted a,b = {min(a_i, b_{3-i})} -- bit-identical to the
//   full per-lane top-4. Post-merge each wave owns 2 queries for radix /
//   compact / gather / GEMV. Grid 2048 blocks -> 8 blocks/CU -> 8 waves/SIMD
//   (round-11 showed 4 waves/SIMD leaves ~40% of VALU issue slots idle).
//   LDS merge buffer (16 KB) is reused for s_nb/s_upd after barrier #2.
// ---------------------------------------------------------------------------
__global__ __launch_bounds__(256) void gravnet_kernel(
    const float* __restrict__ x, const float* __restrict__ coords,
    const float* __restrict__ sq, const float* __restrict__ feats,
    const float* __restrict__ Wo, const float* __restrict__ bo,
    float* __restrict__ out)
{
    int lane = threadIdx.x & 63;
    int w    = threadIdx.x >> 6;              // wave 0..3
    int quad = w >> 1;                        // 0..1: which query-quad
    int half = w & 1;                         // which candidate half
    int qb   = blockIdx.x * 8 + quad * 4;     // quad's first global query
    int b    = (blockIdx.x * 8) >> 12;        // batch (uniform in block)
    int v0   = qb & (VV - 1);

    __shared__ __align__(16) char smem[16384];
    uint4* s_mrg = (uint4*)smem;                       // [16][64] phase 1
    uint2* s_nb  = (uint2*)smem;                       // [8][KK]  phase 2
    float* s_upd = (float*)(smem + 8 * KK * 8);        // [8][192] phase 2

    const float4* cb  = (const float4*)(coords + (size_t)b * VV * 4);
    const float*  sqb = sq + (size_t)b * VV;

    // pair-packed query constants for the quad (lane-uniform)
    float4 cq0 = cb[v0],     cq1 = cb[v0 + 1];
    float4 cq2 = cb[v0 + 2], cq3 = cb[v0 + 3];
    v2f nxA = (v2f){-2.f * cq0.x, -2.f * cq1.x};
    v2f nyA = (v2f){-2.f * cq0.y, -2.f * cq1.y};
    v2f nzA = (v2f){-2.f * cq0.z, -2.f * cq1.z};
    v2f nwA = (v2f){-2.f * cq0.w, -2.f * cq1.w};
    v2f hsA = (v2f){sqb[v0], sqb[v0 + 1]};
    v2f nxB = (v2f){-2.f * cq2.x, -2.f * cq3.x};
    v2f nyB = (v2f){-2.f * cq2.y, -2.f * cq3.y};
    v2f nzB = (v2f){-2.f * cq2.z, -2.f * cq3.z};
    v2f nwB = (v2f){-2.f * cq2.w, -2.f * cq3.w};
    v2f hsB = (v2f){sqb[v0 + 2], sqb[v0 + 3]};

    // per-lane top-4 keys per quad-query, individually named (spill-proof)
    unsigned k00 = ~0u, k01 = ~0u, k02 = ~0u, k03 = ~0u;
    unsigned k10 = ~0u, k11 = ~0u, k12 = ~0u, k13 = ~0u;
    unsigned k20 = ~0u, k21 = ~0u, k22 = ~0u, k23 = ~0u;
    unsigned k30 = ~0u, k31 = ~0u, k32 = ~0u, k33 = ~0u;

    int i0 = half * 32;                        // this wave's candidate half
    #pragma unroll 4
    for (int i = i0; i < i0 + 32; ++i) {
        int u = i * 64 + lane;
        float4 cu = cb[u];
        float squ = sqb[u];
        v2f accA = hsA + (v2f){squ, squ};
        accA = __builtin_elementwise_fma(nxA, (v2f){cu.x, cu.x}, accA);
        accA = __builtin_elementwise_fma(nyA, (v2f){cu.y, cu.y}, accA);
        accA = __builtin_elementwise_fma(nzA, (v2f){cu.z, cu.z}, accA);
        accA = __builtin_elementwise_fma(nwA, (v2f){cu.w, cu.w}, accA);
        v2f accB = hsB + (v2f){squ, squ};
        accB = __builtin_elementwise_fma(nxB, (v2f){cu.x, cu.x}, accB);
        accB = __builtin_elementwise_fma(nyB, (v2f){cu.y, cu.y}, accB);
        accB = __builtin_elementwise_fma(nzB, (v2f){cu.z, cu.z}, accB);
        accB = __builtin_elementwise_fma(nwB, (v2f){cu.w, cu.w}, accB);

        {   // q0: min + 3x med3, depth 1
            float d2 = fmaxf(accA.x, 0.f);
            unsigned k = (__float_as_uint(d2) & 0xFFFFF000u) | (unsigned)u;
            unsigned n1 = umed3(k00, k01, k);
            unsigned n2 = umed3(k01, k02, k);
            unsigned n3 = umed3(k02, k03, k);
            k00 = min(k00, k); k01 = n1; k02 = n2; k03 = n3;
        }
        {   // q1
            float d2 = fmaxf(accA.y, 0.f);
            unsigned k = (__float_as_uint(d2) & 0xFFFFF000u) | (unsigned)u;
            unsigned n1 = umed3(k10, k11, k);
            unsigned n2 = umed3(k11, k12, k);
            unsigned n3 = umed3(k12, k13, k);
            k10 = min(k10, k); k11 = n1; k12 = n2; k13 = n3;
        }
        {   // q2
            float d2 = fmaxf(accB.x, 0.f);
            unsigned k = (__float_as_uint(d2) & 0xFFFFF000u) | (unsigned)u;
            unsigned n1 = umed3(k20, k21, k);
            unsigned n2 = umed3(k21, k22, k);
            unsigned n3 = umed3(k22, k23, k);
            k20 = min(k20, k); k21 = n1; k22 = n2; k23 = n3;
        }
        {   // q3
            float d2 = fmaxf(accB.y, 0.f);
            unsigned k = (__float_as_uint(d2) & 0xFFFFF000u) | (unsigned)u;
            unsigned n1 = umed3(k30, k31, k);
            unsigned n2 = umed3(k31, k32, k);
            unsigned n3 = umed3(k32, k33, k);
            k30 = min(k30, k); k31 = n1; k32 = n2; k33 = n3;
        }
    }

    // --- publish sorted quads (one b128 per query)
    s_mrg[(w * 4 + 0) * 64 + lane] = make_uint4(k00, k01, k02, k03);
    s_mrg[(w * 4 + 1) * 64 + lane] = make_uint4(k10, k11, k12, k13);
    s_mrg[(w * 4 + 2) * 64 + lane] = make_uint4(k20, k21, k22, k23);
    s_mrg[(w * 4 + 3) * 64 + lane] = make_uint4(k30, k31, k32, k33);
    __syncthreads();

    // --- consume partner halves for this wave's 2 post-merge queries
    int p   = w ^ 1;
    int lq0 = half * 2;                        // local query 0..3 within quad
    uint4 pb0 = s_mrg[(p * 4 + lq0)     * 64 + lane];
    uint4 pb1 = s_mrg[(p * 4 + lq0 + 1) * 64 + lane];
    // own regs for local queries lq0, lq0+1 (wave-uniform select)
    unsigned oa0 = half ? k20 : k00, oa1 = half ? k21 : k01;
    unsigned oa2 = half ? k22 : k02, oa3 = half ? k23 : k03;
    unsigned ob0 = half ? k30 : k10, ob1 = half ? k31 : k11;
    unsigned ob2 = half ? k32 : k12, ob3 = half ? k33 : k13;
    __syncthreads();                           // before s_nb/s_upd reuse

    // --- bitonic-partner merge: lowest-4 of two sorted quads
    unsigned d0 = min(oa0, pb0.w), d1 = min(oa1, pb0.z);
    unsigned d2 = min(oa2, pb0.y), d3 = min(oa3, pb0.x);
    unsigned A0 = min(d0, d3), A3 = max(d0, d3);      // A0 = lane min
    unsigned e0 = min(ob0, pb1.w), e1 = min(ob1, pb1.z);
    unsigned e2 = min(ob2, pb1.y), e3 = min(ob3, pb1.x);
    unsigned B0 = min(e0, e3), B3 = max(e0, e3);

    // --- select + compact for the wave's 2 queries
    int s0 = w * 2, s1 = w * 2 + 1;            // LDS slots
    compact4(A0, d1, d2, A3, select_thresh(A0, d1, d2, A3), &s_nb[s0 * KK]);
    compact4(B0, e1, e2, B3, select_thresh(B0, e1, e2, B3), &s_nb[s1 * KK]);
    // s_nb reads below are same-wave: no barrier needed

    // --- gather 39 neighbours x 2 queries
    const float* fb  = feats + (size_t)b * VV * 64;
    const char*  fbl = (const char*)(fb + lane);
    float vmax0 = -INFINITY, vsum0 = 0.f, vmax1 = -INFINITY, vsum1 = 0.f;
    #pragma unroll 6
    for (int j = 0; j < KK - 1; ++j) {
        uint2 n0 = s_nb[s0 * KK + j];          // ds_read_b64 x2
        uint2 n1 = s_nb[s1 * KK + j];
        float f0 = *(const float*)(fbl + n0.x);
        float f1 = *(const float*)(fbl + n1.x);
        float g0 = __uint_as_float(n0.y) * f0;
        float g1 = __uint_as_float(n1.y) * f1;
        vmax0 = fmaxf(vmax0, g0); vsum0 += g0;
        vmax1 = fmaxf(vmax1, g1); vsum1 += g1;
    }

    // --- updated vectors to LDS
    int q0g = qb + lq0, q1g = qb + lq0 + 1;
    s_upd[s0 * 192 + lane]       = x[(size_t)q0g * 64 + lane];
    s_upd[s0 * 192 + 64  + lane] = vmax0;
    s_upd[s0 * 192 + 128 + lane] = vsum0 * (1.0f / 39.0f);
    s_upd[s1 * 192 + lane]       = x[(size_t)q1g * 64 + lane];
    s_upd[s1 * 192 + 64  + lane] = vmax1;
    s_upd[s1 * 192 + 128 + lane] = vsum1 * (1.0f / 39.0f);

    // --- GEMV (192 x 64) x 2: Wo row loaded once, 2 fma each
    float bol = bo[lane];
    float acc0 = bol, acc1 = bol;
    #pragma unroll 4
    for (int j4 = 0; j4 < 48; ++j4) {
        float wo0 = Wo[(j4 * 4 + 0) * 64 + lane];
        float wo1 = Wo[(j4 * 4 + 1) * 64 + lane];
        float wo2 = Wo[(j4 * 4 + 2) * 64 + lane];
        float wo3 = Wo[(j4 * 4 + 3) * 64 + lane];
        float4 u0 = *(const float4*)&s_upd[s0 * 192 + j4 * 4]; // LDS bcast
        float4 u1 = *(const float4*)&s_upd[s1 * 192 + j4 * 4];
        acc0 = fmaf(u0.x, wo0, acc0);  acc1 = fmaf(u1.x, wo0, acc1);
        acc0 = fmaf(u0.y, wo1, acc0);  acc1 = fmaf(u1.y, wo1, acc1);
        acc0 = fmaf(u0.z, wo2, acc0);  acc1 = fmaf(u1.z, wo2, acc1);
        acc0 = fmaf(u0.w, wo3, acc0);  acc1 = fmaf(u1.w, wo3, acc1);
    }
    float e0t = __expf(2.f * acc0);            // tanh = 1 - 2/(e^2x+1)
    float e1t = __expf(2.f * acc1);
    out[(size_t)q0g * 64 + lane] = 1.f - __fdividef(2.f, e0t + 1.f);
    out[(size_t)q1g * 64 + lane] = 1.f - __fdividef(2.f, e1t + 1.f);
}

// ---------------------------------------------------------------------------
extern "C" void kernel_launch(void* const* d_in, const int* in_sizes, int n_in,
                              void* d_out, int out_size, void* d_ws, size_t ws_size,
                              hipStream_t stream)
{
    (void)in_sizes; (void)n_in; (void)out_size; (void)ws_size;
    const float* x  = (const float*)d_in[0];
    const float* Wf = (const float*)d_in[1];
    const float* bf = (const float*)d_in[2];
    const float* Ws = (const float*)d_in[3];
    const float* bs = (const float*)d_in[4];
    const float* Wo = (const float*)d_in[5];
    const float* bo = (const float*)d_in[6];
    float* out = (float*)d_out;

    float* coords = (float*)d_ws;                     // B*V*4  floats (256 KB)
    float* sq     = coords + (size_t)BB * VV * 4;     // B*V    floats (64 KB)
    float* feats  = sq + (size_t)BB * VV;             // B*V*64 floats (4 MB)

    prep_kernel<<<BB * VV / 16, 256, 0, stream>>>(x, Wf, bf, Ws, bs,
                                                  coords, sq, feats);
    gravnet_kernel<<<BB * VV / 8, 256, 0, stream>>>(x, coords, sq, feats,
                                                    Wo, bo, out);
}